// Round 5
// baseline (328.318 us; speedup 1.0000x reference)
//
#include <hip/hip_runtime.h>

// B=2, S=2048, D=1024, H=16, DK=64. Inputs fp32 dict-order, output fp32.
// Round 19: attn — in-block KV-split. 512-thread blocks, 8 waves = 2 teams
// x 4 waves; team tm handles KV [tm*1024, tm*1024+1024) with its own 32KB
// K/V double-buffer (64KB/block, 2 blocks/CU -> 4 waves/SIMD, 2x occupancy
// of R18, zero extra HBM traffic). Flash partials (o,m,l) merged in-block
// via LDS at the end. Max/sum reductions restructured as explicit pairwise
// trees (depth 5) to cut the serial 32-op dependent chains. Keeps: dbuf,
// skewed PV(t-1), defer-max, 5-bit XOR swizzle (R18: conflicts -> 0),
// in-register P via cvt_pk+permlane32_swap, setprio.

typedef __attribute__((ext_vector_type(8))) __bf16 bf16x8;
typedef __attribute__((ext_vector_type(4))) __bf16 bf16x4;
typedef __attribute__((ext_vector_type(8))) float f32x8;
typedef __attribute__((ext_vector_type(4))) float f32x4;
typedef __attribute__((ext_vector_type(16))) float f32x16;
typedef unsigned uv2 __attribute__((ext_vector_type(2)));

#define MFMA16 __builtin_amdgcn_mfma_f32_16x16x32_bf16
#define MFMA32 __builtin_amdgcn_mfma_f32_32x32x16_bf16

union Bf8 { bf16x8 v; __bf16 e[8]; };

__device__ inline f32x4 zero4() { f32x4 z; z[0]=z[1]=z[2]=z[3]=0.f; return z; }
__device__ inline f32x16 zero16() {
    f32x16 z;
#pragma unroll
    for (int i = 0; i < 16; i++) z[i] = 0.f;
    return z;
}

__device__ inline float fast_exp2(float x) {
#if __has_builtin(__builtin_amdgcn_exp2f)
    return __builtin_amdgcn_exp2f(x);
#else
    return __expf(x * 0.6931471805599453f);
#endif
}

#if __has_builtin(__builtin_amdgcn_permlane32_swap)
#define HAVE_PLSWAP 1
#endif

// a_new = [a_lo, b_lo]; b_new = [a_hi, b_hi]  (halves swapped across regs)
__device__ inline void plswap32(unsigned &a, unsigned &b) {
#ifdef HAVE_PLSWAP
    uv2 r = __builtin_amdgcn_permlane32_swap(a, b, false, false);
    a = r[0]; b = r[1];
#else
    unsigned sa = __shfl_xor((int)a, 32), sb = __shfl_xor((int)b, 32);
    bool hi = (threadIdx.x & 32) != 0;
    unsigned na = hi ? sb : a;
    unsigned nb = hi ? b : sa;
    a = na; b = nb;
#endif
}

__device__ inline float red32_max(float x) {
#ifdef HAVE_PLSWAP
    unsigned a = __float_as_uint(x), b = __float_as_uint(x);
    uv2 r = __builtin_amdgcn_permlane32_swap(a, b, false, false);
    return fmaxf(__uint_as_float(r[0]), __uint_as_float(r[1]));
#else
    return fmaxf(x, __shfl_xor(x, 32));
#endif
}
__device__ inline float red32_sum(float x) {
#ifdef HAVE_PLSWAP
    unsigned a = __float_as_uint(x), b = __float_as_uint(x);
    uv2 r = __builtin_amdgcn_permlane32_swap(a, b, false, false);
    return __uint_as_float(r[0]) + __uint_as_float(r[1]);
#else
    return x + __shfl_xor(x, 32);
#endif
}

__device__ inline unsigned pk2(float a, float b) {
    union { unsigned u; __bf16 e[2]; } r;
    r.e[0] = (__bf16)a; r.e[1] = (__bf16)b;
    return r.u;
}

__device__ inline void load_lds16(const void* g, void* l) {
    __builtin_amdgcn_global_load_lds(
        (const __attribute__((address_space(1))) unsigned int*)g,
        (__attribute__((address_space(3))) unsigned int*)l, 16, 0, 0);
}

// ---------------------------------------------------------------------------
// Fused prep. z<4: transpose+convert weight z -> WT[n][k]. z>=4: flat
// fp32->bf16 convert of activation z-4. grid (32,32,7), block 256.
// ---------------------------------------------------------------------------
__global__ __launch_bounds__(256) void prep_all(
        const float* __restrict__ w0, const float* __restrict__ w1,
        const float* __restrict__ w2, const float* __restrict__ w3,
        const float* __restrict__ x0, const float* __restrict__ x1,
        const float* __restrict__ x2,
        __bf16* __restrict__ wt, __bf16* __restrict__ d0,
        __bf16* __restrict__ d1, __bf16* __restrict__ d2) {
    const int z = blockIdx.z, t = threadIdx.x;
    if (z < 4) {
        const float* src = z == 0 ? w0 : z == 1 ? w1 : z == 2 ? w2 : w3;
        __bf16* dst = wt + (size_t)z * 1048576;
        __shared__ float tile[32][33];
        const int tc = t & 31, tr = t >> 5;
        const int r0 = blockIdx.y * 32, c0 = blockIdx.x * 32;
#pragma unroll
        for (int i = 0; i < 4; i++) {
            int r = tr + i * 8;
            tile[r][tc] = src[(size_t)(r0 + r) * 1024 + c0 + tc];
        }
        __syncthreads();
#pragma unroll
        for (int i = 0; i < 4; i++) {
            int r = tr + i * 8;
            dst[(size_t)(c0 + r) * 1024 + r0 + tc] = (__bf16)tile[tc][r];
        }
    } else {
        const float* src = z == 4 ? x0 : z == 5 ? x1 : x2;
        __bf16* dst = z == 4 ? d0 : z == 5 ? d1 : d2;
        int bid = blockIdx.y * 32 + blockIdx.x;
        size_t g = ((size_t)bid * 256 + t) * 16;
#pragma unroll
        for (int h = 0; h < 2; h++) {
            f32x8 a = *(const f32x8*)&src[g + h * 8];
            Bf8 tmp;
#pragma unroll
            for (int j = 0; j < 8; j++) tmp.e[j] = (__bf16)a[j];
            *(bf16x8*)&dst[g + h * 8] = tmp.v;
        }
    }
}

// ---------------------------------------------------------------------------
// FAST GEMM core (128x128, BK=64). Both operands via global_load_lds(16B),
// XOR-swizzled LDS (stride 64, block cb at pc = cb ^ (row&7)). smem (16384
// __bf16 = 32 KB) passed from the kernel so all template instantiations
// share ONE allocation.
// MODE 0: row-major fp32; 1: Q/K head layout; 2: V^T with LDS-transpose.
// ---------------------------------------------------------------------------
template <int MODE, typename OutT>
__device__ inline void gemm_fast_core(__bf16* __restrict__ smem,
                                      const __bf16* __restrict__ A,
                                      const __bf16* __restrict__ Bt,
                                      const float* __restrict__ bias,
                                      OutT* __restrict__ out, float scale) {
    __bf16* As = smem;
    __bf16* Bs = smem + 8192;
    const int t = threadIdx.x;
    const int wave = t >> 6, lane = t & 63, lm = lane & 15, quad = lane >> 4;
    const int m0 = blockIdx.y * 128, n0 = blockIdx.x * 128;
    const int wm = (wave >> 1) * 64, wn = (wave & 1) * 64;

    f32x4 acc[4][4];
#pragma unroll
    for (int i = 0; i < 4; i++)
#pragma unroll
        for (int j = 0; j < 4; j++) acc[i][j] = zero4();

    for (int k0 = 0; k0 < 1024; k0 += 64) {
#pragma unroll
        for (int i = 0; i < 4; i++) {
            int s = i * 256 + t;
            int row = s >> 3, cb = (s & 7) ^ (row & 7);
            size_t goff = (size_t)row * 1024 + k0 + cb * 8;
            load_lds16(&A[(size_t)m0 * 1024 + goff],
                       &As[(size_t)(i * 256 + wave * 64) * 8]);
            load_lds16(&Bt[(size_t)n0 * 1024 + goff],
                       &Bs[(size_t)(i * 256 + wave * 64) * 8]);
        }
        __syncthreads();
#pragma unroll
        for (int ks = 0; ks < 2; ks++) {
            bf16x8 af[4], bfr[4];
#pragma unroll
            for (int mt = 0; mt < 4; mt++)
                af[mt] = *(const bf16x8*)&As[(wm + mt * 16 + lm) * 64 +
                                             (((ks * 4 + quad) ^ (lm & 7)) * 8)];
#pragma unroll
            for (int nt = 0; nt < 4; nt++)
                bfr[nt] = *(const bf16x8*)&Bs[(wn + nt * 16 + lm) * 64 +
                                              (((ks * 4 + quad) ^ (lm & 7)) * 8)];
#pragma unroll
            for (int mt = 0; mt < 4; mt++)
#pragma unroll
                for (int nt = 0; nt < 4; nt++)
                    acc[mt][nt] = MFMA16(af[mt], bfr[nt], acc[mt][nt], 0, 0, 0);
        }
        __syncthreads();
    }

    float bv4[4];
#pragma unroll
    for (int nt = 0; nt < 4; nt++) bv4[nt] = bias[n0 + wn + nt * 16 + lm];

    if (MODE == 2) {
#pragma unroll
        for (int mt = 0; mt < 4; mt++)
#pragma unroll
            for (int r = 0; r < 4; r++) {
                int rr = wm + mt * 16 + quad * 4 + r;
#pragma unroll
                for (int nt = 0; nt < 4; nt++) {
                    int c = wn + nt * 16 + lm;
                    smem[c * 128 + (rr ^ (8 * (c & 15)))] =
                        (__bf16)((acc[mt][nt][r] + bv4[nt]) * scale);
                }
            }
        __syncthreads();
        const int b = m0 >> 11;
#pragma unroll
        for (int it = 0; it < 8; it++) {
            int g = it * 256 + t;
            int c = g >> 4, gr = g & 15;
            bf16x8 v = *(const bf16x8*)&smem[c * 128 + ((gr * 8) ^ (8 * (c & 15)))];
            int col = n0 + c, hh = col >> 6, dk = col & 63;
            int sglob = (m0 & 2047) + gr * 8;
            size_t idx = (size_t)(b * 16 + hh) * 131072 + (size_t)dk * 2048 + sglob;
            *(bf16x8*)&out[idx] = v;
        }
    } else {
#pragma unroll
        for (int mt = 0; mt < 4; mt++) {
#pragma unroll
            for (int r = 0; r < 4; r++) {
                int row = m0 + wm + mt * 16 + quad * 4 + r;
#pragma unroll
                for (int nt = 0; nt < 4; nt++) {
                    int col = n0 + wn + nt * 16 + lm;
                    float val = (acc[mt][nt][r] + bv4[nt]) * scale;
                    size_t idx;
                    if (MODE == 0) {
                        idx = (size_t)row * 1024 + col;
                    } else {
                        int b = row >> 11, s = row & 2047, hh = col >> 6, dk = col & 63;
                        idx = (size_t)(b * 16 + hh) * 131072 + (size_t)s * 64 + dk;
                    }
                    out[idx] = (OutT)val;
                }
            }
        }
    }
}

__global__ __launch_bounds__(256) void proj_fast3(
        const __bf16* __restrict__ xq, const __bf16* __restrict__ xk,
        const __bf16* __restrict__ xv, const __bf16* __restrict__ WT,
        const float* __restrict__ bq, const float* __restrict__ bk,
        const float* __restrict__ bv,
        __bf16* __restrict__ Q, __bf16* __restrict__ K, __bf16* __restrict__ Vt) {
    __shared__ __bf16 smem[16384];
    int z = blockIdx.z;
    if (z == 0)  // fold (1/8)*log2(e): softmax runs in exp2 domain
        gemm_fast_core<1, __bf16>(smem, xq, WT, bq, Q, 0.18033688f);
    else if (z == 1)
        gemm_fast_core<1, __bf16>(smem, xk, WT + 1048576, bk, K, 1.f);
    else
        gemm_fast_core<2, __bf16>(smem, xv, WT + 2097152, bv, Vt, 1.f);
}

// ---------------------------------------------------------------------------
// Out-projection, 128x64 tile (BK=64) -> grid (16,32) = 512 blocks.
// ---------------------------------------------------------------------------
__global__ __launch_bounds__(256) void out_proj_fast64(
        const __bf16* __restrict__ A, const __bf16* __restrict__ Bt,
        const float* __restrict__ bias, float* __restrict__ out) {
    __shared__ __bf16 As[8192];
    __shared__ __bf16 Bs[4096];
    const int t = threadIdx.x;
    const int wave = t >> 6, lane = t & 63, lm = lane & 15, quad = lane >> 4;
    const int m0 = blockIdx.y * 128, n0 = blockIdx.x * 64;
    const int wm = (wave >> 1) * 64, wn = (wave & 1) * 32;

    f32x4 acc[4][2];
#pragma unroll
    for (int i = 0; i < 4; i++) { acc[i][0] = zero4(); acc[i][1] = zero4(); }

    for (int k0 = 0; k0 < 1024; k0 += 64) {
#pragma unroll
        for (int i = 0; i < 4; i++) {
            int s = i * 256 + t;
            int row = s >> 3, cb = (s & 7) ^ (row & 7);
            load_lds16(&A[(size_t)(m0 + row) * 1024 + k0 + cb * 8],
                       &As[(size_t)(i * 256 + wave * 64) * 8]);
            if (i < 2)
                load_lds16(&Bt[(size_t)(n0 + row) * 1024 + k0 + cb * 8],
                           &Bs[(size_t)(i * 256 + wave * 64) * 8]);
        }
        __syncthreads();
#pragma unroll
        for (int ks = 0; ks < 2; ks++) {
            bf16x8 af[4], bfr[2];
#pragma unroll
            for (int mt = 0; mt < 4; mt++)
                af[mt] = *(const bf16x8*)&As[(wm + mt * 16 + lm) * 64 +
                                             (((ks * 4 + quad) ^ (lm & 7)) * 8)];
#pragma unroll
            for (int nt = 0; nt < 2; nt++)
                bfr[nt] = *(const bf16x8*)&Bs[(wn + nt * 16 + lm) * 64 +
                                              (((ks * 4 + quad) ^ (lm & 7)) * 8)];
#pragma unroll
            for (int mt = 0; mt < 4; mt++)
#pragma unroll
                for (int nt = 0; nt < 2; nt++)
                    acc[mt][nt] = MFMA16(af[mt], bfr[nt], acc[mt][nt], 0, 0, 0);
        }
        __syncthreads();
    }

    float bv2[2];
#pragma unroll
    for (int nt = 0; nt < 2; nt++) bv2[nt] = bias[n0 + wn + nt * 16 + lm];

#pragma unroll
    for (int mt = 0; mt < 4; mt++)
#pragma unroll
        for (int r = 0; r < 4; r++) {
            int row = m0 + wm + mt * 16 + quad * 4 + r;
#pragma unroll
            for (int nt = 0; nt < 2; nt++) {
                int col = n0 + wn + nt * 16 + lm;
                out[(size_t)row * 1024 + col] = acc[mt][nt][r] + bv2[nt];
            }
        }
}

// ---------------------------------------------------------------------------
// Flash attention, 32x32x16 MFMA, in-register P, in-block KV-split.
// grid (16,32), block 512 = 2 teams x 4 waves x 32 q-rows. Team tm covers
// KV [tm*1024, (tm+1)*1024), 16 tiles of 64. LDS 64KB: per-team
// [K0|K1|V0|V1] x 8KB. Per-team skewed dbuf identical to R18. Final
// in-block flash merge of the two (o,m,l) partial sets through LDS.
// ---------------------------------------------------------------------------
__global__ __launch_bounds__(512, 4) void attn_kernel(
        const __bf16* __restrict__ Q, const __bf16* __restrict__ K,
        const __bf16* __restrict__ Vt, __bf16* __restrict__ O) {
    __shared__ __bf16 smem[32768];  // 64 KB
    const int t = threadIdx.x;
    const int wave = t >> 6, lane = t & 63;
    const int l31 = lane & 31, h = lane >> 5;
    const int team = wave >> 2, w4 = wave & 3;
    const int tt = t & 255;               // thread-in-team
    const unsigned Tb = team * 16384;     // team LDS base (bf16 elems)
    const int kvbase = team * 1024;
    const int q0 = blockIdx.x * 128;
    const int bh = blockIdx.y;
    const size_t base = (size_t)bh * 131072;

    // Q fragment: B-operand of 32x32x16, col=q=l31, k=kst*16+8h+j
    bf16x8 bq[4];
    {
        int qrow = q0 + w4 * 32 + l31;
#pragma unroll
        for (int kst = 0; kst < 4; kst++)
            bq[kst] = *(const bf16x8*)&Q[base + (size_t)qrow * 64 + kst * 16 + h * 8];
    }

    // Fragment LDS element-offsets (row = m*32+l31; 5-bit swizzle)
    unsigned fo[2][4];
#pragma unroll
    for (int m = 0; m < 2; m++)
#pragma unroll
        for (int k = 0; k < 4; k++)
            fo[m][k] = (unsigned)((m * 32 + l31) * 64 +
                       (((k * 2 + h) ^ (l31 & 7) ^ ((l31 >> 3) & 3)) * 8));

    // Staging offsets (per-thread constants, team-relative)
    unsigned kdst[2], ksrc[2], vsrc[2];
#pragma unroll
    for (int i = 0; i < 2; i++) {
        int s = i * 256 + tt;
        int row = s >> 3, cb = (s & 7) ^ (row & 7) ^ ((row >> 3) & 3);
        kdst[i] = Tb + (unsigned)((i * 256 + w4 * 64) * 8);
        ksrc[i] = (unsigned)(row * 64 + cb * 8);    // + kv0*64
        vsrc[i] = (unsigned)(row * 2048 + cb * 8);  // + kv0
    }

    float m_run = -1e30f, l_run = 0.f;
    f32x16 o_acc[2];
    o_acc[0] = zero16();
    o_acc[1] = zero16();
    bf16x8 bp[4];  // P(t-1) as PV B-fragments, lives in regs across barrier

    // prologue: K(first tile) into team buf 0
#pragma unroll
    for (int i = 0; i < 2; i++)
        load_lds16(&K[base + (size_t)kvbase * 64 + ksrc[i]], &smem[kdst[i]]);
    __syncthreads();

    auto body = [&](int it, int cur) {
        const int kv0 = kvbase + it * 64;
        // stage K(t+1) into team buf cur^1, V(t) into team buf cur
        if (it < 15) {
#pragma unroll
            for (int i = 0; i < 2; i++)
                load_lds16(&K[base + (size_t)(kv0 + 64) * 64 + ksrc[i]],
                           &smem[(cur ^ 1) * 4096 + kdst[i]]);
        }
#pragma unroll
        for (int i = 0; i < 2; i++)
            load_lds16(&Vt[base + (size_t)kv0 + vsrc[i]],
                       &smem[8192 + cur * 4096 + kdst[i]]);

        // ---- QK^T: A=K (m=kv rows), B=Q (n=q) -> D[kv][q] ----
        f32x16 sc[2];
        sc[0] = zero16();
        sc[1] = zero16();
        __builtin_amdgcn_s_setprio(1);
#pragma unroll
        for (int mtk = 0; mtk < 2; mtk++)
#pragma unroll
            for (int kst = 0; kst < 4; kst++) {
                bf16x8 ak = *(const bf16x8*)&smem[Tb + cur * 4096 + fo[mtk][kst]];
                sc[mtk] = MFMA32(ak, bq[kst], sc[mtk], 0, 0, 0);
            }
        // ---- PV(t-1): A=Vt (m=dk rows), B=P(t-1) in regs ----
        if (it > 0) {
#pragma unroll
            for (int kb = 0; kb < 4; kb++)
#pragma unroll
                for (int mtd = 0; mtd < 2; mtd++) {
                    bf16x8 av = *(const bf16x8*)&smem[Tb + 8192 + (cur ^ 1) * 4096 +
                                                      fo[mtd][kb]];
                    o_acc[mtd] = MFMA32(av, bp[kb], o_acc[mtd], 0, 0, 0);
                }
        }
        __builtin_amdgcn_s_setprio(0);

        // ---- online softmax (exp2 domain), tree reductions ----
        float tm16[16];
#pragma unroll
        for (int i = 0; i < 16; i++) tm16[i] = fmaxf(sc[0][i], sc[1][i]);
#pragma unroll
        for (int st = 8; st >= 1; st >>= 1)
#pragma unroll
            for (int i = 0; i < st; i++) tm16[i] = fmaxf(tm16[i], tm16[i + st]);
        float mx = red32_max(tm16[0]);
        float mo = m_run;
        if (__all(mx <= mo + 8.f)) {
            // defer-max: keep old m, no rescale (P bounded by 2^8)
#pragma unroll
            for (int mtk = 0; mtk < 2; mtk++)
#pragma unroll
                for (int r = 0; r < 16; r++)
                    sc[mtk][r] = fast_exp2(sc[mtk][r] - mo);
        } else {
            float mn = fmaxf(mo, mx);
            float alpha = fast_exp2(mo - mn);
            m_run = mn;
#pragma unroll
            for (int mtk = 0; mtk < 2; mtk++)
#pragma unroll
                for (int r = 0; r < 16; r++)
                    sc[mtk][r] = fast_exp2(sc[mtk][r] - mn);
            l_run *= alpha;
#pragma unroll
            for (int mtd = 0; mtd < 2; mtd++)
#pragma unroll
                for (int r = 0; r < 16; r++) o_acc[mtd][r] *= alpha;
        }
        {
            float s16[16];
#pragma unroll
            for (int i = 0; i < 16; i++) s16[i] = sc[0][i] + sc[1][i];
#pragma unroll
            for (int st = 8; st >= 1; st >>= 1)
#pragma unroll
                for (int i = 0; i < st; i++) s16[i] += s16[i + st];
            l_run += s16[0];  // per-lane partial; cross-lane reduce deferred
        }

        // ---- P(t) -> PV B-fragments in registers ----
#pragma unroll
        for (int kb = 0; kb < 4; kb++) {
            const int mt = kb >> 1, g = (kb & 1) * 2;
            unsigned A0 = pk2(sc[mt][g * 4 + 0], sc[mt][g * 4 + 1]);
            unsigned A1 = pk2(sc[mt][g * 4 + 2], sc[mt][g * 4 + 3]);
            unsigned B0 = pk2(sc[mt][g * 4 + 4], sc[mt][g * 4 + 5]);
            unsigned B1 = pk2(sc[mt][g * 4 + 6], sc[mt][g * 4 + 7]);
            plswap32(A0, B0);
            plswap32(A1, B1);
            union { unsigned u[4]; bf16x8 v; } bb;
            bb.u[0] = A0; bb.u[1] = A1; bb.u[2] = B0; bb.u[3] = B1;
            bp[kb] = bb.v;
        }

        __syncthreads();  // K(t+1), V(t) landed; buffers safe to flip
    };

    for (int it = 0; it < 16; it += 2) {
        body(it, 0);
        body(it + 1, 1);
    }

    // ---- final PV(15): P in bp, V(15) in team V buf 1 ----
    {
        __builtin_amdgcn_s_setprio(1);
#pragma unroll
        for (int kb = 0; kb < 4; kb++)
#pragma unroll
            for (int mtd = 0; mtd < 2; mtd++) {
                bf16x8 av = *(const bf16x8*)&smem[Tb + 8192 + 4096 + fo[mtd][kb]];
                o_acc[mtd] = MFMA32(av, bp[kb], o_acc[mtd], 0, 0, 0);
            }
        __builtin_amdgcn_s_setprio(0);
    }
    __syncthreads();  // all K/V reads done; LDS reusable for the merge

    // ---- in-block flash merge: team1 publishes (o1, m1, l1); team0 combines,
    //      normalizes, transposes through LDS, writes O. ----
    float l_loc = red32_sum(l_run);
    float m_loc = m_run;
    float* fsm = (float*)smem;   // 16384 f32
    const int qi = w4 * 32 + l31;
    if (team == 1) {
        // o1: [128 q][68 pad] f32 @ fsm[0..8704); ml1: @ fsm[8704..8960)
#pragma unroll
        for (int mtd = 0; mtd < 2; mtd++)
#pragma unroll
            for (int c = 0; c < 4; c++)
#pragma unroll
                for (int r2 = 0; r2 < 4; r2++)
                    fsm[qi * 68 + mtd * 32 + c * 8 + h * 4 + r2] =
                        o_acc[mtd][c * 4 + r2];
        if (h == 0) {
            fsm[8704 + qi * 2]     = m_loc;
            fsm[8704 + qi * 2 + 1] = l_loc;
        }
    }
    __syncthreads();
    if (team == 0) {
        float m1 = fsm[8704 + qi * 2];
        float l1 = fsm[8704 + qi * 2 + 1];
        float mm = fmaxf(m_loc, m1);
        float a0 = fast_exp2(m_loc - mm);
        float a1 = fast_exp2(m1 - mm);
        float linv = 1.f / (l_loc * a0 + l1 * a1);
        a0 *= linv; a1 *= linv;
        // Osc bf16 scratch @ element 17920 (byte 35840), after the f32 merge
        // regions; stride-68 rows, wave-private.
        __bf16* Osc = &smem[17920 + w4 * 2176];
#pragma unroll
        for (int mtd = 0; mtd < 2; mtd++)
#pragma unroll
            for (int c = 0; c < 4; c++) {
                bf16x4 pk4;
#pragma unroll
                for (int r2 = 0; r2 < 4; r2++) {
                    int d = mtd * 32 + c * 8 + h * 4 + r2;
                    pk4[r2] = (__bf16)(o_acc[mtd][c * 4 + r2] * a0 +
                                       fsm[qi * 68 + d] * a1);
                }
                *(bf16x4*)&Osc[l31 * 68 + mtd * 32 + c * 8 + h * 4] = pk4;
            }
        __asm__ volatile("" ::: "memory");
        const int b = bh >> 4, hh = bh & 15;
        int ql = lane >> 1, half = lane & 1;
        int srow = q0 + w4 * 32 + ql;
#pragma unroll
        for (int j = 0; j < 4; j++) {
            bf16x8 v = *(const bf16x8*)&Osc[ql * 68 + half * 32 + j * 8];
            *(bf16x8*)&O[(size_t)(b * 2048 + srow) * 1024 + hh * 64 + half * 32 + j * 8] = v;
        }
    }
}

// ---------------------------------------------------------------------------
extern "C" void kernel_launch(void* const* d_in, const int* in_sizes, int n_in,
                              void* d_out, int out_size, void* d_ws, size_t ws_size,
                              hipStream_t stream) {
    if (ws_size < ((size_t)40 << 20)) return;

    const float* query = (const float*)d_in[0];
    const float* key_  = (const float*)d_in[1];
    const float* value = (const float*)d_in[2];
    const float* wq = (const float*)d_in[3];
    const float* bq = (const float*)d_in[4];
    const float* wk = (const float*)d_in[5];
    const float* bk = (const float*)d_in[6];
    const float* wv = (const float*)d_in[7];
    const float* bv = (const float*)d_in[8];
    const float* wo = (const float*)d_in[9];
    const float* bo = (const float*)d_in[10];
    float* out = (float*)d_out;

    char* ws = (char*)d_ws;
    __bf16* WT  = (__bf16*)(ws);                       // 8 MB
    __bf16* Qw  = (__bf16*)(ws + ((size_t)8  << 20));
    __bf16* Kw  = (__bf16*)(ws + ((size_t)16 << 20));
    __bf16* Vtw = (__bf16*)(ws + ((size_t)24 << 20));
    __bf16* Ow  = (__bf16*)(ws + ((size_t)32 << 20));  // 8 MB

    // bf16 activation scratch: Xq aliases Ow (dead until attn writes it);
    // Xk/Xv live in d_out (16.8 MB fp32; dead until out_proj writes it).
    __bf16* Xq = Ow;
    __bf16* Xk = (__bf16*)d_out;
    __bf16* Xv = (__bf16*)d_out + 4194304;

    prep_all<<<dim3(32, 32, 7), dim3(256), 0, stream>>>(
        wq, wk, wv, wo, query, key_, value, WT, Xq, Xk, Xv);
    proj_fast3<<<dim3(8, 32, 3), dim3(256), 0, stream>>>(
        Xq, Xk, Xv, WT, bq, bk, bv, Qw, Kw, Vtw);
    attn_kernel<<<dim3(16, 32), dim3(512), 0, stream>>>(Qw, Kw, Vtw, Ow);
    out_proj_fast64<<<dim3(16, 32), dim3(256), 0, stream>>>(
        Ow, WT + 3 * 1048576, bo, out);
}

// Round 6
// 232.851 us; speedup vs baseline: 1.4100x; 1.4100x over previous
//
#include <hip/hip_runtime.h>

// B=2, S=2048, D=1024, H=16, DK=64. Inputs fp32 dict-order, output fp32.
// Round 20: R19's in-block KV-split, fixed for the spill disaster.
// R19 post-mortem: __launch_bounds__(512,4) gave a 64-VGPR cap -> full
// scratch spill (WRITE_SIZE 8MB->372MB, attn 60->157us). Fix:
// __launch_bounds__(512,2) (128-VGPR cap = the 4-waves/SIMD occupancy
// step), fo[] shrunk to 4 regs (mt*2048 folds into ds-offset immediate),
// reduction trees use 8 temps. Teams, per-team 32KB dbuf, skewed PV(t-1),
// defer-max, 5-bit swizzle (conflicts=0), in-reg P via cvt_pk+permlane32,
// in-block flash merge all retained.

typedef __attribute__((ext_vector_type(8))) __bf16 bf16x8;
typedef __attribute__((ext_vector_type(4))) __bf16 bf16x4;
typedef __attribute__((ext_vector_type(8))) float f32x8;
typedef __attribute__((ext_vector_type(4))) float f32x4;
typedef __attribute__((ext_vector_type(16))) float f32x16;
typedef unsigned uv2 __attribute__((ext_vector_type(2)));

#define MFMA16 __builtin_amdgcn_mfma_f32_16x16x32_bf16
#define MFMA32 __builtin_amdgcn_mfma_f32_32x32x16_bf16

union Bf8 { bf16x8 v; __bf16 e[8]; };

__device__ inline f32x4 zero4() { f32x4 z; z[0]=z[1]=z[2]=z[3]=0.f; return z; }
__device__ inline f32x16 zero16() {
    f32x16 z;
#pragma unroll
    for (int i = 0; i < 16; i++) z[i] = 0.f;
    return z;
}

__device__ inline float fast_exp2(float x) {
#if __has_builtin(__builtin_amdgcn_exp2f)
    return __builtin_amdgcn_exp2f(x);
#else
    return __expf(x * 0.6931471805599453f);
#endif
}

#if __has_builtin(__builtin_amdgcn_permlane32_swap)
#define HAVE_PLSWAP 1
#endif

// a_new = [a_lo, b_lo]; b_new = [a_hi, b_hi]  (halves swapped across regs)
__device__ inline void plswap32(unsigned &a, unsigned &b) {
#ifdef HAVE_PLSWAP
    uv2 r = __builtin_amdgcn_permlane32_swap(a, b, false, false);
    a = r[0]; b = r[1];
#else
    unsigned sa = __shfl_xor((int)a, 32), sb = __shfl_xor((int)b, 32);
    bool hi = (threadIdx.x & 32) != 0;
    unsigned na = hi ? sb : a;
    unsigned nb = hi ? b : sa;
    a = na; b = nb;
#endif
}

__device__ inline float red32_max(float x) {
#ifdef HAVE_PLSWAP
    unsigned a = __float_as_uint(x), b = __float_as_uint(x);
    uv2 r = __builtin_amdgcn_permlane32_swap(a, b, false, false);
    return fmaxf(__uint_as_float(r[0]), __uint_as_float(r[1]));
#else
    return fmaxf(x, __shfl_xor(x, 32));
#endif
}
__device__ inline float red32_sum(float x) {
#ifdef HAVE_PLSWAP
    unsigned a = __float_as_uint(x), b = __float_as_uint(x);
    uv2 r = __builtin_amdgcn_permlane32_swap(a, b, false, false);
    return __uint_as_float(r[0]) + __uint_as_float(r[1]);
#else
    return x + __shfl_xor(x, 32);
#endif
}

__device__ inline unsigned pk2(float a, float b) {
    union { unsigned u; __bf16 e[2]; } r;
    r.e[0] = (__bf16)a; r.e[1] = (__bf16)b;
    return r.u;
}

__device__ inline void load_lds16(const void* g, void* l) {
    __builtin_amdgcn_global_load_lds(
        (const __attribute__((address_space(1))) unsigned int*)g,
        (__attribute__((address_space(3))) unsigned int*)l, 16, 0, 0);
}

// ---------------------------------------------------------------------------
// Fused prep. z<4: transpose+convert weight z -> WT[n][k]. z>=4: flat
// fp32->bf16 convert of activation z-4. grid (32,32,7), block 256.
// ---------------------------------------------------------------------------
__global__ __launch_bounds__(256) void prep_all(
        const float* __restrict__ w0, const float* __restrict__ w1,
        const float* __restrict__ w2, const float* __restrict__ w3,
        const float* __restrict__ x0, const float* __restrict__ x1,
        const float* __restrict__ x2,
        __bf16* __restrict__ wt, __bf16* __restrict__ d0,
        __bf16* __restrict__ d1, __bf16* __restrict__ d2) {
    const int z = blockIdx.z, t = threadIdx.x;
    if (z < 4) {
        const float* src = z == 0 ? w0 : z == 1 ? w1 : z == 2 ? w2 : w3;
        __bf16* dst = wt + (size_t)z * 1048576;
        __shared__ float tile[32][33];
        const int tc = t & 31, tr = t >> 5;
        const int r0 = blockIdx.y * 32, c0 = blockIdx.x * 32;
#pragma unroll
        for (int i = 0; i < 4; i++) {
            int r = tr + i * 8;
            tile[r][tc] = src[(size_t)(r0 + r) * 1024 + c0 + tc];
        }
        __syncthreads();
#pragma unroll
        for (int i = 0; i < 4; i++) {
            int r = tr + i * 8;
            dst[(size_t)(c0 + r) * 1024 + r0 + tc] = (__bf16)tile[tc][r];
        }
    } else {
        const float* src = z == 4 ? x0 : z == 5 ? x1 : x2;
        __bf16* dst = z == 4 ? d0 : z == 5 ? d1 : d2;
        int bid = blockIdx.y * 32 + blockIdx.x;
        size_t g = ((size_t)bid * 256 + t) * 16;
#pragma unroll
        for (int h = 0; h < 2; h++) {
            f32x8 a = *(const f32x8*)&src[g + h * 8];
            Bf8 tmp;
#pragma unroll
            for (int j = 0; j < 8; j++) tmp.e[j] = (__bf16)a[j];
            *(bf16x8*)&dst[g + h * 8] = tmp.v;
        }
    }
}

// ---------------------------------------------------------------------------
// FAST GEMM core (128x128, BK=64). Both operands via global_load_lds(16B),
// XOR-swizzled LDS (stride 64, block cb at pc = cb ^ (row&7)). smem (16384
// __bf16 = 32 KB) passed from the kernel so all template instantiations
// share ONE allocation.
// MODE 0: row-major fp32; 1: Q/K head layout; 2: V^T with LDS-transpose.
// ---------------------------------------------------------------------------
template <int MODE, typename OutT>
__device__ inline void gemm_fast_core(__bf16* __restrict__ smem,
                                      const __bf16* __restrict__ A,
                                      const __bf16* __restrict__ Bt,
                                      const float* __restrict__ bias,
                                      OutT* __restrict__ out, float scale) {
    __bf16* As = smem;
    __bf16* Bs = smem + 8192;
    const int t = threadIdx.x;
    const int wave = t >> 6, lane = t & 63, lm = lane & 15, quad = lane >> 4;
    const int m0 = blockIdx.y * 128, n0 = blockIdx.x * 128;
    const int wm = (wave >> 1) * 64, wn = (wave & 1) * 64;

    f32x4 acc[4][4];
#pragma unroll
    for (int i = 0; i < 4; i++)
#pragma unroll
        for (int j = 0; j < 4; j++) acc[i][j] = zero4();

    for (int k0 = 0; k0 < 1024; k0 += 64) {
#pragma unroll
        for (int i = 0; i < 4; i++) {
            int s = i * 256 + t;
            int row = s >> 3, cb = (s & 7) ^ (row & 7);
            size_t goff = (size_t)row * 1024 + k0 + cb * 8;
            load_lds16(&A[(size_t)m0 * 1024 + goff],
                       &As[(size_t)(i * 256 + wave * 64) * 8]);
            load_lds16(&Bt[(size_t)n0 * 1024 + goff],
                       &Bs[(size_t)(i * 256 + wave * 64) * 8]);
        }
        __syncthreads();
#pragma unroll
        for (int ks = 0; ks < 2; ks++) {
            bf16x8 af[4], bfr[4];
#pragma unroll
            for (int mt = 0; mt < 4; mt++)
                af[mt] = *(const bf16x8*)&As[(wm + mt * 16 + lm) * 64 +
                                             (((ks * 4 + quad) ^ (lm & 7)) * 8)];
#pragma unroll
            for (int nt = 0; nt < 4; nt++)
                bfr[nt] = *(const bf16x8*)&Bs[(wn + nt * 16 + lm) * 64 +
                                              (((ks * 4 + quad) ^ (lm & 7)) * 8)];
#pragma unroll
            for (int mt = 0; mt < 4; mt++)
#pragma unroll
                for (int nt = 0; nt < 4; nt++)
                    acc[mt][nt] = MFMA16(af[mt], bfr[nt], acc[mt][nt], 0, 0, 0);
        }
        __syncthreads();
    }

    float bv4[4];
#pragma unroll
    for (int nt = 0; nt < 4; nt++) bv4[nt] = bias[n0 + wn + nt * 16 + lm];

    if (MODE == 2) {
#pragma unroll
        for (int mt = 0; mt < 4; mt++)
#pragma unroll
            for (int r = 0; r < 4; r++) {
                int rr = wm + mt * 16 + quad * 4 + r;
#pragma unroll
                for (int nt = 0; nt < 4; nt++) {
                    int c = wn + nt * 16 + lm;
                    smem[c * 128 + (rr ^ (8 * (c & 15)))] =
                        (__bf16)((acc[mt][nt][r] + bv4[nt]) * scale);
                }
            }
        __syncthreads();
        const int b = m0 >> 11;
#pragma unroll
        for (int it = 0; it < 8; it++) {
            int g = it * 256 + t;
            int c = g >> 4, gr = g & 15;
            bf16x8 v = *(const bf16x8*)&smem[c * 128 + ((gr * 8) ^ (8 * (c & 15)))];
            int col = n0 + c, hh = col >> 6, dk = col & 63;
            int sglob = (m0 & 2047) + gr * 8;
            size_t idx = (size_t)(b * 16 + hh) * 131072 + (size_t)dk * 2048 + sglob;
            *(bf16x8*)&out[idx] = v;
        }
    } else {
#pragma unroll
        for (int mt = 0; mt < 4; mt++) {
#pragma unroll
            for (int r = 0; r < 4; r++) {
                int row = m0 + wm + mt * 16 + quad * 4 + r;
#pragma unroll
                for (int nt = 0; nt < 4; nt++) {
                    int col = n0 + wn + nt * 16 + lm;
                    float val = (acc[mt][nt][r] + bv4[nt]) * scale;
                    size_t idx;
                    if (MODE == 0) {
                        idx = (size_t)row * 1024 + col;
                    } else {
                        int b = row >> 11, s = row & 2047, hh = col >> 6, dk = col & 63;
                        idx = (size_t)(b * 16 + hh) * 131072 + (size_t)s * 64 + dk;
                    }
                    out[idx] = (OutT)val;
                }
            }
        }
    }
}

__global__ __launch_bounds__(256) void proj_fast3(
        const __bf16* __restrict__ xq, const __bf16* __restrict__ xk,
        const __bf16* __restrict__ xv, const __bf16* __restrict__ WT,
        const float* __restrict__ bq, const float* __restrict__ bk,
        const float* __restrict__ bv,
        __bf16* __restrict__ Q, __bf16* __restrict__ K, __bf16* __restrict__ Vt) {
    __shared__ __bf16 smem[16384];
    int z = blockIdx.z;
    if (z == 0)  // fold (1/8)*log2(e): softmax runs in exp2 domain
        gemm_fast_core<1, __bf16>(smem, xq, WT, bq, Q, 0.18033688f);
    else if (z == 1)
        gemm_fast_core<1, __bf16>(smem, xk, WT + 1048576, bk, K, 1.f);
    else
        gemm_fast_core<2, __bf16>(smem, xv, WT + 2097152, bv, Vt, 1.f);
}

// ---------------------------------------------------------------------------
// Out-projection, 128x64 tile (BK=64) -> grid (16,32) = 512 blocks.
// ---------------------------------------------------------------------------
__global__ __launch_bounds__(256) void out_proj_fast64(
        const __bf16* __restrict__ A, const __bf16* __restrict__ Bt,
        const float* __restrict__ bias, float* __restrict__ out) {
    __shared__ __bf16 As[8192];
    __shared__ __bf16 Bs[4096];
    const int t = threadIdx.x;
    const int wave = t >> 6, lane = t & 63, lm = lane & 15, quad = lane >> 4;
    const int m0 = blockIdx.y * 128, n0 = blockIdx.x * 64;
    const int wm = (wave >> 1) * 64, wn = (wave & 1) * 32;

    f32x4 acc[4][2];
#pragma unroll
    for (int i = 0; i < 4; i++) { acc[i][0] = zero4(); acc[i][1] = zero4(); }

    for (int k0 = 0; k0 < 1024; k0 += 64) {
#pragma unroll
        for (int i = 0; i < 4; i++) {
            int s = i * 256 + t;
            int row = s >> 3, cb = (s & 7) ^ (row & 7);
            load_lds16(&A[(size_t)(m0 + row) * 1024 + k0 + cb * 8],
                       &As[(size_t)(i * 256 + wave * 64) * 8]);
            if (i < 2)
                load_lds16(&Bt[(size_t)(n0 + row) * 1024 + k0 + cb * 8],
                           &Bs[(size_t)(i * 256 + wave * 64) * 8]);
        }
        __syncthreads();
#pragma unroll
        for (int ks = 0; ks < 2; ks++) {
            bf16x8 af[4], bfr[2];
#pragma unroll
            for (int mt = 0; mt < 4; mt++)
                af[mt] = *(const bf16x8*)&As[(wm + mt * 16 + lm) * 64 +
                                             (((ks * 4 + quad) ^ (lm & 7)) * 8)];
#pragma unroll
            for (int nt = 0; nt < 2; nt++)
                bfr[nt] = *(const bf16x8*)&Bs[(wn + nt * 16 + lm) * 64 +
                                              (((ks * 4 + quad) ^ (lm & 7)) * 8)];
#pragma unroll
            for (int mt = 0; mt < 4; mt++)
#pragma unroll
                for (int nt = 0; nt < 2; nt++)
                    acc[mt][nt] = MFMA16(af[mt], bfr[nt], acc[mt][nt], 0, 0, 0);
        }
        __syncthreads();
    }

    float bv2[2];
#pragma unroll
    for (int nt = 0; nt < 2; nt++) bv2[nt] = bias[n0 + wn + nt * 16 + lm];

#pragma unroll
    for (int mt = 0; mt < 4; mt++)
#pragma unroll
        for (int r = 0; r < 4; r++) {
            int row = m0 + wm + mt * 16 + quad * 4 + r;
#pragma unroll
            for (int nt = 0; nt < 2; nt++) {
                int col = n0 + wn + nt * 16 + lm;
                out[(size_t)row * 1024 + col] = acc[mt][nt][r] + bv2[nt];
            }
        }
}

// ---------------------------------------------------------------------------
// Flash attention, 32x32x16 MFMA, in-register P, in-block KV-split.
// grid (16,32), block 512 = 2 teams x 4 waves x 32 q-rows. Team tm covers
// KV [tm*1024, (tm+1)*1024), 16 tiles of 64. LDS 64KB: per-team
// [K0|K1|V0|V1] x 8KB. Per-team skewed dbuf identical to R18. Final
// in-block flash merge of the two (o,m,l) partial sets through LDS.
// __launch_bounds__(512,2): 128-VGPR cap (the 4-waves/SIMD step) WITHOUT
// the 64-cap spill disaster of (512,4) [R19: WRITE_SIZE 372MB].
// ---------------------------------------------------------------------------
__global__ __launch_bounds__(512, 2) void attn_kernel(
        const __bf16* __restrict__ Q, const __bf16* __restrict__ K,
        const __bf16* __restrict__ Vt, __bf16* __restrict__ O) {
    __shared__ __bf16 smem[32768];  // 64 KB
    const int t = threadIdx.x;
    const int wave = t >> 6, lane = t & 63;
    const int l31 = lane & 31, h = lane >> 5;
    const int team = wave >> 2, w4 = wave & 3;
    const int tt = t & 255;               // thread-in-team
    const unsigned Tb = team * 16384;     // team LDS base (bf16 elems)
    const int kvbase = team * 1024;
    const int q0 = blockIdx.x * 128;
    const int bh = blockIdx.y;
    const size_t base = (size_t)bh * 131072;

    // Q fragment: B-operand of 32x32x16, col=q=l31, k=kst*16+8h+j
    bf16x8 bq[4];
    {
        int qrow = q0 + w4 * 32 + l31;
#pragma unroll
        for (int kst = 0; kst < 4; kst++)
            bq[kst] = *(const bf16x8*)&Q[base + (size_t)qrow * 64 + kst * 16 + h * 8];
    }

    // Fragment LDS element-offsets for m=0 rows (l31); m=1 adds 2048 elems
    // (4096 B), a compile-time ds-offset immediate.
    unsigned fo[4];
#pragma unroll
    for (int k = 0; k < 4; k++)
        fo[k] = (unsigned)(l31 * 64 +
                (((k * 2 + h) ^ (l31 & 7) ^ ((l31 >> 3) & 3)) * 8));

    // Staging offsets (per-thread constants, team-relative)
    unsigned kdst[2], ksrc[2], vsrc[2];
#pragma unroll
    for (int i = 0; i < 2; i++) {
        int s = i * 256 + tt;
        int row = s >> 3, cb = (s & 7) ^ (row & 7) ^ ((row >> 3) & 3);
        kdst[i] = Tb + (unsigned)((i * 256 + w4 * 64) * 8);
        ksrc[i] = (unsigned)(row * 64 + cb * 8);    // + kv0*64
        vsrc[i] = (unsigned)(row * 2048 + cb * 8);  // + kv0
    }

    float m_run = -1e30f, l_run = 0.f;
    f32x16 o_acc[2];
    o_acc[0] = zero16();
    o_acc[1] = zero16();
    bf16x8 bp[4];  // P(t-1) as PV B-fragments, lives in regs across barrier

    // prologue: K(first tile) into team buf 0
#pragma unroll
    for (int i = 0; i < 2; i++)
        load_lds16(&K[base + (size_t)kvbase * 64 + ksrc[i]], &smem[kdst[i]]);
    __syncthreads();

    auto body = [&](int it, int cur) {
        const int kv0 = kvbase + it * 64;
        // stage K(t+1) into team buf cur^1, V(t) into team buf cur
        if (it < 15) {
#pragma unroll
            for (int i = 0; i < 2; i++)
                load_lds16(&K[base + (size_t)(kv0 + 64) * 64 + ksrc[i]],
                           &smem[(cur ^ 1) * 4096 + kdst[i]]);
        }
#pragma unroll
        for (int i = 0; i < 2; i++)
            load_lds16(&Vt[base + (size_t)kv0 + vsrc[i]],
                       &smem[8192 + cur * 4096 + kdst[i]]);

        // ---- QK^T: A=K (m=kv rows), B=Q (n=q) -> D[kv][q] ----
        f32x16 sc[2];
        sc[0] = zero16();
        sc[1] = zero16();
        __builtin_amdgcn_s_setprio(1);
#pragma unroll
        for (int mtk = 0; mtk < 2; mtk++)
#pragma unroll
            for (int kst = 0; kst < 4; kst++) {
                bf16x8 ak = *(const bf16x8*)&smem[Tb + cur * 4096 +
                                                  mtk * 2048 + fo[kst]];
                sc[mtk] = MFMA32(ak, bq[kst], sc[mtk], 0, 0, 0);
            }
        // ---- PV(t-1): A=Vt (m=dk rows), B=P(t-1) in regs ----
        if (it > 0) {
#pragma unroll
            for (int kb = 0; kb < 4; kb++)
#pragma unroll
                for (int mtd = 0; mtd < 2; mtd++) {
                    bf16x8 av = *(const bf16x8*)&smem[Tb + 8192 + (cur ^ 1) * 4096 +
                                                      mtd * 2048 + fo[kb]];
                    o_acc[mtd] = MFMA32(av, bp[kb], o_acc[mtd], 0, 0, 0);
                }
        }
        __builtin_amdgcn_s_setprio(0);

        // ---- online softmax (exp2 domain), 8-temp tree reductions ----
        float tr8[8];
#pragma unroll
        for (int i = 0; i < 8; i++)
            tr8[i] = fmaxf(fmaxf(sc[0][i], sc[0][i + 8]),
                           fmaxf(sc[1][i], sc[1][i + 8]));
#pragma unroll
        for (int st = 4; st >= 1; st >>= 1)
#pragma unroll
            for (int i = 0; i < st; i++) tr8[i] = fmaxf(tr8[i], tr8[i + st]);
        float mx = red32_max(tr8[0]);
        float mo = m_run;
        if (__all(mx <= mo + 8.f)) {
            // defer-max: keep old m, no rescale (P bounded by 2^8)
#pragma unroll
            for (int mtk = 0; mtk < 2; mtk++)
#pragma unroll
                for (int r = 0; r < 16; r++)
                    sc[mtk][r] = fast_exp2(sc[mtk][r] - mo);
        } else {
            float mn = fmaxf(mo, mx);
            float alpha = fast_exp2(mo - mn);
            m_run = mn;
#pragma unroll
            for (int mtk = 0; mtk < 2; mtk++)
#pragma unroll
                for (int r = 0; r < 16; r++)
                    sc[mtk][r] = fast_exp2(sc[mtk][r] - mn);
            l_run *= alpha;
#pragma unroll
            for (int mtd = 0; mtd < 2; mtd++)
#pragma unroll
                for (int r = 0; r < 16; r++) o_acc[mtd][r] *= alpha;
        }
#pragma unroll
        for (int i = 0; i < 8; i++)
            tr8[i] = (sc[0][i] + sc[0][i + 8]) + (sc[1][i] + sc[1][i + 8]);
#pragma unroll
        for (int st = 4; st >= 1; st >>= 1)
#pragma unroll
            for (int i = 0; i < st; i++) tr8[i] += tr8[i + st];
        l_run += tr8[0];  // per-lane partial; cross-lane reduce deferred

        // ---- P(t) -> PV B-fragments in registers ----
#pragma unroll
        for (int kb = 0; kb < 4; kb++) {
            const int mt = kb >> 1, g = (kb & 1) * 2;
            unsigned A0 = pk2(sc[mt][g * 4 + 0], sc[mt][g * 4 + 1]);
            unsigned A1 = pk2(sc[mt][g * 4 + 2], sc[mt][g * 4 + 3]);
            unsigned B0 = pk2(sc[mt][g * 4 + 4], sc[mt][g * 4 + 5]);
            unsigned B1 = pk2(sc[mt][g * 4 + 6], sc[mt][g * 4 + 7]);
            plswap32(A0, B0);
            plswap32(A1, B1);
            union { unsigned u[4]; bf16x8 v; } bb;
            bb.u[0] = A0; bb.u[1] = A1; bb.u[2] = B0; bb.u[3] = B1;
            bp[kb] = bb.v;
        }

        __syncthreads();  // K(t+1), V(t) landed; buffers safe to flip
    };

    for (int it = 0; it < 16; it += 2) {
        body(it, 0);
        body(it + 1, 1);
    }

    // ---- final PV(15): P in bp, V(15) in team V buf 1 ----
    {
        __builtin_amdgcn_s_setprio(1);
#pragma unroll
        for (int kb = 0; kb < 4; kb++)
#pragma unroll
            for (int mtd = 0; mtd < 2; mtd++) {
                bf16x8 av = *(const bf16x8*)&smem[Tb + 8192 + 4096 +
                                                  mtd * 2048 + fo[kb]];
                o_acc[mtd] = MFMA32(av, bp[kb], o_acc[mtd], 0, 0, 0);
            }
        __builtin_amdgcn_s_setprio(0);
    }
    __syncthreads();  // all K/V reads done; LDS reusable for the merge

    // ---- in-block flash merge: team1 publishes (o1, m1, l1); team0 combines,
    //      normalizes, transposes through LDS, writes O. ----
    float l_loc = red32_sum(l_run);
    float m_loc = m_run;
    float* fsm = (float*)smem;   // 16384 f32
    const int qi = w4 * 32 + l31;
    if (team == 1) {
        // o1: [128 q][68 pad] f32 @ fsm[0..8704); ml1: @ fsm[8704..8960)
#pragma unroll
        for (int mtd = 0; mtd < 2; mtd++)
#pragma unroll
            for (int c = 0; c < 4; c++)
#pragma unroll
                for (int r2 = 0; r2 < 4; r2++)
                    fsm[qi * 68 + mtd * 32 + c * 8 + h * 4 + r2] =
                        o_acc[mtd][c * 4 + r2];
        if (h == 0) {
            fsm[8704 + qi * 2]     = m_loc;
            fsm[8704 + qi * 2 + 1] = l_loc;
        }
    }
    __syncthreads();
    if (team == 0) {
        float m1 = fsm[8704 + qi * 2];
        float l1 = fsm[8704 + qi * 2 + 1];
        float mm = fmaxf(m_loc, m1);
        float a0 = fast_exp2(m_loc - mm);
        float a1 = fast_exp2(m1 - mm);
        float linv = 1.f / (l_loc * a0 + l1 * a1);
        a0 *= linv; a1 *= linv;
        // Osc bf16 scratch @ element 17920 (byte 35840), after the f32 merge
        // regions; stride-68 rows, wave-private.
        __bf16* Osc = &smem[17920 + w4 * 2176];
#pragma unroll
        for (int mtd = 0; mtd < 2; mtd++)
#pragma unroll
            for (int c = 0; c < 4; c++) {
                bf16x4 pk4;
#pragma unroll
                for (int r2 = 0; r2 < 4; r2++) {
                    int d = mtd * 32 + c * 8 + h * 4 + r2;
                    pk4[r2] = (__bf16)(o_acc[mtd][c * 4 + r2] * a0 +
                                       fsm[qi * 68 + d] * a1);
                }
                *(bf16x4*)&Osc[l31 * 68 + mtd * 32 + c * 8 + h * 4] = pk4;
            }
        __asm__ volatile("" ::: "memory");
        const int b = bh >> 4, hh = bh & 15;
        int ql = lane >> 1, half = lane & 1;
        int srow = q0 + w4 * 32 + ql;
#pragma unroll
        for (int j = 0; j < 4; j++) {
            bf16x8 v = *(const bf16x8*)&Osc[ql * 68 + half * 32 + j * 8];
            *(bf16x8*)&O[(size_t)(b * 2048 + srow) * 1024 + hh * 64 + half * 32 + j * 8] = v;
        }
    }
}

// ---------------------------------------------------------------------------
extern "C" void kernel_launch(void* const* d_in, const int* in_sizes, int n_in,
                              void* d_out, int out_size, void* d_ws, size_t ws_size,
                              hipStream_t stream) {
    if (ws_size < ((size_t)40 << 20)) return;

    const float* query = (const float*)d_in[0];
    const float* key_  = (const float*)d_in[1];
    const float* value = (const float*)d_in[2];
    const float* wq = (const float*)d_in[3];
    const float* bq = (const float*)d_in[4];
    const float* wk = (const float*)d_in[5];
    const float* bk = (const float*)d_in[6];
    const float* wv = (const float*)d_in[7];
    const float* bv = (const float*)d_in[8];
    const float* wo = (const float*)d_in[9];
    const float* bo = (const float*)d_in[10];
    float* out = (float*)d_out;

    char* ws = (char*)d_ws;
    __bf16* WT  = (__bf16*)(ws);                       // 8 MB
    __bf16* Qw  = (__bf16*)(ws + ((size_t)8  << 20));
    __bf16* Kw  = (__bf16*)(ws + ((size_t)16 << 20));
    __bf16* Vtw = (__bf16*)(ws + ((size_t)24 << 20));
    __bf16* Ow  = (__bf16*)(ws + ((size_t)32 << 20));  // 8 MB

    // bf16 activation scratch: Xq aliases Ow (dead until attn writes it);
    // Xk/Xv live in d_out (16.8 MB fp32; dead until out_proj writes it).
    __bf16* Xq = Ow;
    __bf16* Xk = (__bf16*)d_out;
    __bf16* Xv = (__bf16*)d_out + 4194304;

    prep_all<<<dim3(32, 32, 7), dim3(256), 0, stream>>>(
        wq, wk, wv, wo, query, key_, value, WT, Xq, Xk, Xv);
    proj_fast3<<<dim3(8, 32, 3), dim3(256), 0, stream>>>(
        Xq, Xk, Xv, WT, bq, bk, bv, Qw, Kw, Vtw);
    attn_kernel<<<dim3(16, 32), dim3(512), 0, stream>>>(Qw, Kw, Vtw, Ow);
    out_proj_fast64<<<dim3(16, 32), dim3(256), 0, stream>>>(
        Ow, WT + 3 * 1048576, bo, out);
}

// Round 7
// 224.202 us; speedup vs baseline: 1.4644x; 1.0386x over previous
//
#include <hip/hip_runtime.h>

// B=2, S=2048, D=1024, H=16, DK=64. Inputs fp32 dict-order, output fp32.
// Round 21: revert attn to R18's proven 4-wave structure (R20's in-block
// KV-split regressed: teams share per-iter barriers -> lockstep, occupancy
// gain never materialized). New: softmax drops the per-iter max tree.
// m_run is pinned at 0 on the fast path (scores ~N(0,1.4) in exp2 domain;
// p = exp2(sc) <= ~400); the guard is the SUM (computed anyway for l):
// if su > 2^20, rare path rescales by alpha = 1/pmax (recovered from p).
// Deletes 31 fmax + permlane_max + branch per iter (~100 VALU cyc of
// serial chain). Keeps: dbuf, skewed PV(t-1), 5-bit swizzle (conflicts=0),
// in-register P via cvt_pk+permlane32_swap, setprio, 2-unrolled loop.

typedef __attribute__((ext_vector_type(8))) __bf16 bf16x8;
typedef __attribute__((ext_vector_type(4))) __bf16 bf16x4;
typedef __attribute__((ext_vector_type(8))) float f32x8;
typedef __attribute__((ext_vector_type(4))) float f32x4;
typedef __attribute__((ext_vector_type(16))) float f32x16;
typedef unsigned uv2 __attribute__((ext_vector_type(2)));

#define MFMA16 __builtin_amdgcn_mfma_f32_16x16x32_bf16
#define MFMA32 __builtin_amdgcn_mfma_f32_32x32x16_bf16

union Bf8 { bf16x8 v; __bf16 e[8]; };

__device__ inline f32x4 zero4() { f32x4 z; z[0]=z[1]=z[2]=z[3]=0.f; return z; }
__device__ inline f32x16 zero16() {
    f32x16 z;
#pragma unroll
    for (int i = 0; i < 16; i++) z[i] = 0.f;
    return z;
}

__device__ inline float fast_exp2(float x) {
#if __has_builtin(__builtin_amdgcn_exp2f)
    return __builtin_amdgcn_exp2f(x);
#else
    return __expf(x * 0.6931471805599453f);
#endif
}

#if __has_builtin(__builtin_amdgcn_permlane32_swap)
#define HAVE_PLSWAP 1
#endif

// a_new = [a_lo, b_lo]; b_new = [a_hi, b_hi]  (halves swapped across regs)
__device__ inline void plswap32(unsigned &a, unsigned &b) {
#ifdef HAVE_PLSWAP
    uv2 r = __builtin_amdgcn_permlane32_swap(a, b, false, false);
    a = r[0]; b = r[1];
#else
    unsigned sa = __shfl_xor((int)a, 32), sb = __shfl_xor((int)b, 32);
    bool hi = (threadIdx.x & 32) != 0;
    unsigned na = hi ? sb : a;
    unsigned nb = hi ? b : sa;
    a = na; b = nb;
#endif
}

__device__ inline float red32_sum(float x) {
#ifdef HAVE_PLSWAP
    unsigned a = __float_as_uint(x), b = __float_as_uint(x);
    uv2 r = __builtin_amdgcn_permlane32_swap(a, b, false, false);
    return __uint_as_float(r[0]) + __uint_as_float(r[1]);
#else
    return x + __shfl_xor(x, 32);
#endif
}

__device__ inline unsigned pk2(float a, float b) {
    union { unsigned u; __bf16 e[2]; } r;
    r.e[0] = (__bf16)a; r.e[1] = (__bf16)b;
    return r.u;
}

__device__ inline void load_lds16(const void* g, void* l) {
    __builtin_amdgcn_global_load_lds(
        (const __attribute__((address_space(1))) unsigned int*)g,
        (__attribute__((address_space(3))) unsigned int*)l, 16, 0, 0);
}

// ---------------------------------------------------------------------------
// Fused prep. z<4: transpose+convert weight z -> WT[n][k]. z>=4: flat
// fp32->bf16 convert of activation z-4. grid (32,32,7), block 256.
// ---------------------------------------------------------------------------
__global__ __launch_bounds__(256) void prep_all(
        const float* __restrict__ w0, const float* __restrict__ w1,
        const float* __restrict__ w2, const float* __restrict__ w3,
        const float* __restrict__ x0, const float* __restrict__ x1,
        const float* __restrict__ x2,
        __bf16* __restrict__ wt, __bf16* __restrict__ d0,
        __bf16* __restrict__ d1, __bf16* __restrict__ d2) {
    const int z = blockIdx.z, t = threadIdx.x;
    if (z < 4) {
        const float* src = z == 0 ? w0 : z == 1 ? w1 : z == 2 ? w2 : w3;
        __bf16* dst = wt + (size_t)z * 1048576;
        __shared__ float tile[32][33];
        const int tc = t & 31, tr = t >> 5;
        const int r0 = blockIdx.y * 32, c0 = blockIdx.x * 32;
#pragma unroll
        for (int i = 0; i < 4; i++) {
            int r = tr + i * 8;
            tile[r][tc] = src[(size_t)(r0 + r) * 1024 + c0 + tc];
        }
        __syncthreads();
#pragma unroll
        for (int i = 0; i < 4; i++) {
            int r = tr + i * 8;
            dst[(size_t)(c0 + r) * 1024 + r0 + tc] = (__bf16)tile[tc][r];
        }
    } else {
        const float* src = z == 4 ? x0 : z == 5 ? x1 : x2;
        __bf16* dst = z == 4 ? d0 : z == 5 ? d1 : d2;
        int bid = blockIdx.y * 32 + blockIdx.x;
        size_t g = ((size_t)bid * 256 + t) * 16;
#pragma unroll
        for (int h = 0; h < 2; h++) {
            f32x8 a = *(const f32x8*)&src[g + h * 8];
            Bf8 tmp;
#pragma unroll
            for (int j = 0; j < 8; j++) tmp.e[j] = (__bf16)a[j];
            *(bf16x8*)&dst[g + h * 8] = tmp.v;
        }
    }
}

// ---------------------------------------------------------------------------
// FAST GEMM core (128x128, BK=64). Both operands via global_load_lds(16B),
// XOR-swizzled LDS (stride 64, block cb at pc = cb ^ (row&7)). smem (16384
// __bf16 = 32 KB) passed from the kernel so all template instantiations
// share ONE allocation.
// MODE 0: row-major fp32; 1: Q/K head layout; 2: V^T with LDS-transpose.
// ---------------------------------------------------------------------------
template <int MODE, typename OutT>
__device__ inline void gemm_fast_core(__bf16* __restrict__ smem,
                                      const __bf16* __restrict__ A,
                                      const __bf16* __restrict__ Bt,
                                      const float* __restrict__ bias,
                                      OutT* __restrict__ out, float scale) {
    __bf16* As = smem;
    __bf16* Bs = smem + 8192;
    const int t = threadIdx.x;
    const int wave = t >> 6, lane = t & 63, lm = lane & 15, quad = lane >> 4;
    const int m0 = blockIdx.y * 128, n0 = blockIdx.x * 128;
    const int wm = (wave >> 1) * 64, wn = (wave & 1) * 64;

    f32x4 acc[4][4];
#pragma unroll
    for (int i = 0; i < 4; i++)
#pragma unroll
        for (int j = 0; j < 4; j++) acc[i][j] = zero4();

    for (int k0 = 0; k0 < 1024; k0 += 64) {
#pragma unroll
        for (int i = 0; i < 4; i++) {
            int s = i * 256 + t;
            int row = s >> 3, cb = (s & 7) ^ (row & 7);
            size_t goff = (size_t)row * 1024 + k0 + cb * 8;
            load_lds16(&A[(size_t)m0 * 1024 + goff],
                       &As[(size_t)(i * 256 + wave * 64) * 8]);
            load_lds16(&Bt[(size_t)n0 * 1024 + goff],
                       &Bs[(size_t)(i * 256 + wave * 64) * 8]);
        }
        __syncthreads();
#pragma unroll
        for (int ks = 0; ks < 2; ks++) {
            bf16x8 af[4], bfr[4];
#pragma unroll
            for (int mt = 0; mt < 4; mt++)
                af[mt] = *(const bf16x8*)&As[(wm + mt * 16 + lm) * 64 +
                                             (((ks * 4 + quad) ^ (lm & 7)) * 8)];
#pragma unroll
            for (int nt = 0; nt < 4; nt++)
                bfr[nt] = *(const bf16x8*)&Bs[(wn + nt * 16 + lm) * 64 +
                                              (((ks * 4 + quad) ^ (lm & 7)) * 8)];
#pragma unroll
            for (int mt = 0; mt < 4; mt++)
#pragma unroll
                for (int nt = 0; nt < 4; nt++)
                    acc[mt][nt] = MFMA16(af[mt], bfr[nt], acc[mt][nt], 0, 0, 0);
        }
        __syncthreads();
    }

    float bv4[4];
#pragma unroll
    for (int nt = 0; nt < 4; nt++) bv4[nt] = bias[n0 + wn + nt * 16 + lm];

    if (MODE == 2) {
#pragma unroll
        for (int mt = 0; mt < 4; mt++)
#pragma unroll
            for (int r = 0; r < 4; r++) {
                int rr = wm + mt * 16 + quad * 4 + r;
#pragma unroll
                for (int nt = 0; nt < 4; nt++) {
                    int c = wn + nt * 16 + lm;
                    smem[c * 128 + (rr ^ (8 * (c & 15)))] =
                        (__bf16)((acc[mt][nt][r] + bv4[nt]) * scale);
                }
            }
        __syncthreads();
        const int b = m0 >> 11;
#pragma unroll
        for (int it = 0; it < 8; it++) {
            int g = it * 256 + t;
            int c = g >> 4, gr = g & 15;
            bf16x8 v = *(const bf16x8*)&smem[c * 128 + ((gr * 8) ^ (8 * (c & 15)))];
            int col = n0 + c, hh = col >> 6, dk = col & 63;
            int sglob = (m0 & 2047) + gr * 8;
            size_t idx = (size_t)(b * 16 + hh) * 131072 + (size_t)dk * 2048 + sglob;
            *(bf16x8*)&out[idx] = v;
        }
    } else {
#pragma unroll
        for (int mt = 0; mt < 4; mt++) {
#pragma unroll
            for (int r = 0; r < 4; r++) {
                int row = m0 + wm + mt * 16 + quad * 4 + r;
#pragma unroll
                for (int nt = 0; nt < 4; nt++) {
                    int col = n0 + wn + nt * 16 + lm;
                    float val = (acc[mt][nt][r] + bv4[nt]) * scale;
                    size_t idx;
                    if (MODE == 0) {
                        idx = (size_t)row * 1024 + col;
                    } else {
                        int b = row >> 11, s = row & 2047, hh = col >> 6, dk = col & 63;
                        idx = (size_t)(b * 16 + hh) * 131072 + (size_t)s * 64 + dk;
                    }
                    out[idx] = (OutT)val;
                }
            }
        }
    }
}

__global__ __launch_bounds__(256) void proj_fast3(
        const __bf16* __restrict__ xq, const __bf16* __restrict__ xk,
        const __bf16* __restrict__ xv, const __bf16* __restrict__ WT,
        const float* __restrict__ bq, const float* __restrict__ bk,
        const float* __restrict__ bv,
        __bf16* __restrict__ Q, __bf16* __restrict__ K, __bf16* __restrict__ Vt) {
    __shared__ __bf16 smem[16384];
    int z = blockIdx.z;
    if (z == 0)  // fold (1/8)*log2(e): softmax runs in exp2 domain
        gemm_fast_core<1, __bf16>(smem, xq, WT, bq, Q, 0.18033688f);
    else if (z == 1)
        gemm_fast_core<1, __bf16>(smem, xk, WT + 1048576, bk, K, 1.f);
    else
        gemm_fast_core<2, __bf16>(smem, xv, WT + 2097152, bv, Vt, 1.f);
}

// ---------------------------------------------------------------------------
// Out-projection, 128x64 tile (BK=64) -> grid (16,32) = 512 blocks.
// ---------------------------------------------------------------------------
__global__ __launch_bounds__(256) void out_proj_fast64(
        const __bf16* __restrict__ A, const __bf16* __restrict__ Bt,
        const float* __restrict__ bias, float* __restrict__ out) {
    __shared__ __bf16 As[8192];
    __shared__ __bf16 Bs[4096];
    const int t = threadIdx.x;
    const int wave = t >> 6, lane = t & 63, lm = lane & 15, quad = lane >> 4;
    const int m0 = blockIdx.y * 128, n0 = blockIdx.x * 64;
    const int wm = (wave >> 1) * 64, wn = (wave & 1) * 32;

    f32x4 acc[4][2];
#pragma unroll
    for (int i = 0; i < 4; i++) { acc[i][0] = zero4(); acc[i][1] = zero4(); }

    for (int k0 = 0; k0 < 1024; k0 += 64) {
#pragma unroll
        for (int i = 0; i < 4; i++) {
            int s = i * 256 + t;
            int row = s >> 3, cb = (s & 7) ^ (row & 7);
            load_lds16(&A[(size_t)(m0 + row) * 1024 + k0 + cb * 8],
                       &As[(size_t)(i * 256 + wave * 64) * 8]);
            if (i < 2)
                load_lds16(&Bt[(size_t)(n0 + row) * 1024 + k0 + cb * 8],
                           &Bs[(size_t)(i * 256 + wave * 64) * 8]);
        }
        __syncthreads();
#pragma unroll
        for (int ks = 0; ks < 2; ks++) {
            bf16x8 af[4], bfr[2];
#pragma unroll
            for (int mt = 0; mt < 4; mt++)
                af[mt] = *(const bf16x8*)&As[(wm + mt * 16 + lm) * 64 +
                                             (((ks * 4 + quad) ^ (lm & 7)) * 8)];
#pragma unroll
            for (int nt = 0; nt < 2; nt++)
                bfr[nt] = *(const bf16x8*)&Bs[(wn + nt * 16 + lm) * 64 +
                                              (((ks * 4 + quad) ^ (lm & 7)) * 8)];
#pragma unroll
            for (int mt = 0; mt < 4; mt++)
#pragma unroll
                for (int nt = 0; nt < 2; nt++)
                    acc[mt][nt] = MFMA16(af[mt], bfr[nt], acc[mt][nt], 0, 0, 0);
        }
        __syncthreads();
    }

    float bv2[2];
#pragma unroll
    for (int nt = 0; nt < 2; nt++) bv2[nt] = bias[n0 + wn + nt * 16 + lm];

#pragma unroll
    for (int mt = 0; mt < 4; mt++)
#pragma unroll
        for (int r = 0; r < 4; r++) {
            int row = m0 + wm + mt * 16 + quad * 4 + r;
#pragma unroll
            for (int nt = 0; nt < 2; nt++) {
                int col = n0 + wn + nt * 16 + lm;
                out[(size_t)row * 1024 + col] = acc[mt][nt][r] + bv2[nt];
            }
        }
}

// ---------------------------------------------------------------------------
// Flash attention, 32x32x16 MFMA, P fully in registers.
// grid (16,32), block 256 = 4 waves x 32 q-rows. KVBLK=64, 32 iters
// (2-unrolled: cur is compile-time). LDS: K dbuf 2x8KB + V dbuf 2x8KB = 32KB.
// 5-bit row swizzle on K/V: pc = cb ^ (row&7) ^ ((row>>3)&3).
// Softmax: m pinned at 0 (exp2 domain, data-bounded); su-guarded rare
// rescale path for adversarial inputs. No per-iter max tree.
// Skew: iter t = stage K(t+1),V(t) | QK(t) | PV(t-1) | softmax(t) |
//       P->regs (cvt_pk + permlane32_swap) | barrier.
// ---------------------------------------------------------------------------
__global__ __launch_bounds__(256, 2) void attn_kernel(
        const __bf16* __restrict__ Q, const __bf16* __restrict__ K,
        const __bf16* __restrict__ Vt, __bf16* __restrict__ O) {
    __shared__ __bf16 smem[16384];  // [Ks0|Ks1|Vs0|Vs1] x 4096 bf16
    const int t = threadIdx.x;
    const int wave = t >> 6, lane = t & 63;
    const int l31 = lane & 31, h = lane >> 5;
    const int q0 = blockIdx.x * 128;
    const int bh = blockIdx.y;
    const size_t base = (size_t)bh * 131072;

    // Q fragment: B-operand of 32x32x16, col=q=l31, k=kst*16+8h+j
    bf16x8 bq[4];
    {
        int qrow = q0 + wave * 32 + l31;
#pragma unroll
        for (int kst = 0; kst < 4; kst++)
            bq[kst] = *(const bf16x8*)&Q[base + (size_t)qrow * 64 + kst * 16 + h * 8];
    }

    // Fragment LDS element-offsets (row = m*32+l31; 5-bit swizzle).
    // m=1 adds 2048 elems (4096 B) as a compile-time immediate.
    unsigned fo[4];
#pragma unroll
    for (int k = 0; k < 4; k++)
        fo[k] = (unsigned)(l31 * 64 +
                (((k * 2 + h) ^ (l31 & 7) ^ ((l31 >> 3) & 3)) * 8));

    // Staging offsets (per-thread constants)
    unsigned kdst[2], ksrc[2], vsrc[2];
#pragma unroll
    for (int i = 0; i < 2; i++) {
        int s = i * 256 + t;
        int row = s >> 3, cb = (s & 7) ^ (row & 7) ^ ((row >> 3) & 3);
        kdst[i] = (unsigned)((i * 256 + wave * 64) * 8);
        ksrc[i] = (unsigned)(row * 64 + cb * 8);    // + kv0*64
        vsrc[i] = (unsigned)(row * 2048 + cb * 8);  // + kv0
    }

    float m_run = 0.f, l_run = 0.f;  // m stays 0 unless su-guard trips
    f32x16 o_acc[2];
    o_acc[0] = zero16();
    o_acc[1] = zero16();
    bf16x8 bp[4];  // P(t-1) as PV B-fragments, lives in regs across barrier

    // prologue: K(0) into buf 0
#pragma unroll
    for (int i = 0; i < 2; i++)
        load_lds16(&K[base + ksrc[i]], &smem[kdst[i]]);
    __syncthreads();

    auto body = [&](int it, int cur) {
        const int kv0 = it * 64;
        // stage K(t+1) into buf cur^1, V(t) into buf cur
        if (it < 31) {
#pragma unroll
            for (int i = 0; i < 2; i++)
                load_lds16(&K[base + (size_t)(kv0 + 64) * 64 + ksrc[i]],
                           &smem[(cur ^ 1) * 4096 + kdst[i]]);
        }
#pragma unroll
        for (int i = 0; i < 2; i++)
            load_lds16(&Vt[base + (size_t)kv0 + vsrc[i]],
                       &smem[8192 + cur * 4096 + kdst[i]]);

        // ---- QK^T: A=K (m=kv rows), B=Q (n=q) -> D[kv][q] ----
        f32x16 sc[2];
        sc[0] = zero16();
        sc[1] = zero16();
        __builtin_amdgcn_s_setprio(1);
#pragma unroll
        for (int mtk = 0; mtk < 2; mtk++)
#pragma unroll
            for (int kst = 0; kst < 4; kst++) {
                bf16x8 ak = *(const bf16x8*)&smem[cur * 4096 + mtk * 2048 + fo[kst]];
                sc[mtk] = MFMA32(ak, bq[kst], sc[mtk], 0, 0, 0);
            }
        // ---- PV(t-1): A=Vt (m=dk rows), B=P(t-1) in regs ----
        if (it > 0) {
#pragma unroll
            for (int kb = 0; kb < 4; kb++)
#pragma unroll
                for (int mtd = 0; mtd < 2; mtd++) {
                    bf16x8 av = *(const bf16x8*)&smem[8192 + (cur ^ 1) * 4096 +
                                                      mtd * 2048 + fo[kb]];
                    o_acc[mtd] = MFMA32(av, bp[kb], o_acc[mtd], 0, 0, 0);
                }
        }
        __builtin_amdgcn_s_setprio(0);

        // ---- softmax (exp2 domain): p = exp2(sc - m_run), m_run ~ 0 ----
#pragma unroll
        for (int mtk = 0; mtk < 2; mtk++)
#pragma unroll
            for (int r = 0; r < 16; r++)
                sc[mtk][r] = fast_exp2(sc[mtk][r] - m_run);
        float tr8[8];
#pragma unroll
        for (int i = 0; i < 8; i++)
            tr8[i] = (sc[0][i] + sc[0][i + 8]) + (sc[1][i] + sc[1][i + 8]);
#pragma unroll
        for (int st = 4; st >= 1; st >>= 1)
#pragma unroll
            for (int i = 0; i < st; i++) tr8[i] += tr8[i + st];
        float su = tr8[0];
        if (!__all(su <= 1048576.f)) {
            // rare: scores jumped; rescale so pmax -> 1
            float pm8[8];
#pragma unroll
            for (int i = 0; i < 8; i++)
                pm8[i] = fmaxf(fmaxf(sc[0][i], sc[0][i + 8]),
                               fmaxf(sc[1][i], sc[1][i + 8]));
#pragma unroll
            for (int st = 4; st >= 1; st >>= 1)
#pragma unroll
                for (int i = 0; i < st; i++) pm8[i] = fmaxf(pm8[i], pm8[i + st]);
            float pmax = pm8[0];
#ifdef HAVE_PLSWAP
            {
                unsigned a = __float_as_uint(pmax), b = a;
                uv2 rr = __builtin_amdgcn_permlane32_swap(a, b, false, false);
                pmax = fmaxf(__uint_as_float(rr[0]), __uint_as_float(rr[1]));
            }
#else
            pmax = fmaxf(pmax, __shfl_xor(pmax, 32));
#endif
            float alpha = 1.f / pmax;
            m_run += __log2f(pmax);
#pragma unroll
            for (int mtk = 0; mtk < 2; mtk++)
#pragma unroll
                for (int r = 0; r < 16; r++) sc[mtk][r] *= alpha;
#pragma unroll
            for (int mtd = 0; mtd < 2; mtd++)
#pragma unroll
                for (int r = 0; r < 16; r++) o_acc[mtd][r] *= alpha;
            l_run *= alpha;
            su *= alpha;
        }
        l_run += su;  // per-lane partial; cross-lane reduce deferred

        // ---- P(t) -> PV B-fragments in registers ----
#pragma unroll
        for (int kb = 0; kb < 4; kb++) {
            const int mt = kb >> 1, g = (kb & 1) * 2;
            unsigned A0 = pk2(sc[mt][g * 4 + 0], sc[mt][g * 4 + 1]);
            unsigned A1 = pk2(sc[mt][g * 4 + 2], sc[mt][g * 4 + 3]);
            unsigned B0 = pk2(sc[mt][g * 4 + 4], sc[mt][g * 4 + 5]);
            unsigned B1 = pk2(sc[mt][g * 4 + 6], sc[mt][g * 4 + 7]);
            plswap32(A0, B0);
            plswap32(A1, B1);
            union { unsigned u[4]; bf16x8 v; } bb;
            bb.u[0] = A0; bb.u[1] = A1; bb.u[2] = B0; bb.u[3] = B1;
            bp[kb] = bb.v;
        }

        __syncthreads();  // K(t+1), V(t) landed; buffers safe to flip
    };

    for (int it = 0; it < 32; it += 2) {
        body(it, 0);
        body(it + 1, 1);
    }

    // ---- final PV(31): P in bp, V(31) in Vs buf 1 ----
    {
        __builtin_amdgcn_s_setprio(1);
#pragma unroll
        for (int kb = 0; kb < 4; kb++)
#pragma unroll
            for (int mtd = 0; mtd < 2; mtd++) {
                bf16x8 av = *(const bf16x8*)&smem[8192 + 4096 + mtd * 2048 + fo[kb]];
                o_acc[mtd] = MFMA32(av, bp[kb], o_acc[mtd], 0, 0, 0);
            }
        __builtin_amdgcn_s_setprio(0);
    }
    __syncthreads();  // all K/V reads done; LDS reusable as O scratch

    // ---- normalize + LDS transpose-stage (stride 68) + coalesced write ----
    {
        float inv = 1.f / red32_sum(l_run);
        __bf16* Osc = &smem[wave * 2176];  // 32 rows x 68, wave-private
#pragma unroll
        for (int mtd = 0; mtd < 2; mtd++)
#pragma unroll
            for (int c = 0; c < 4; c++) {
                bf16x4 pk4;
#pragma unroll
                for (int r2 = 0; r2 < 4; r2++)
                    pk4[r2] = (__bf16)(o_acc[mtd][c * 4 + r2] * inv);
                // dk = mtd*32 + c*8 + h*4 + r2
                *(bf16x4*)&Osc[l31 * 68 + mtd * 32 + c * 8 + h * 4] = pk4;
            }
        __asm__ volatile("" ::: "memory");
        const int b = bh >> 4, hh = bh & 15;
        int ql = lane >> 1, half = lane & 1;
        int srow = q0 + wave * 32 + ql;
#pragma unroll
        for (int j = 0; j < 4; j++) {
            bf16x8 v = *(const bf16x8*)&Osc[ql * 68 + half * 32 + j * 8];
            *(bf16x8*)&O[(size_t)(b * 2048 + srow) * 1024 + hh * 64 + half * 32 + j * 8] = v;
        }
    }
}

// ---------------------------------------------------------------------------
extern "C" void kernel_launch(void* const* d_in, const int* in_sizes, int n_in,
                              void* d_out, int out_size, void* d_ws, size_t ws_size,
                              hipStream_t stream) {
    if (ws_size < ((size_t)40 << 20)) return;

    const float* query = (const float*)d_in[0];
    const float* key_  = (const float*)d_in[1];
    const float* value = (const float*)d_in[2];
    const float* wq = (const float*)d_in[3];
    const float* bq = (const float*)d_in[4];
    const float* wk = (const float*)d_in[5];
    const float* bk = (const float*)d_in[6];
    const float* wv = (const float*)d_in[7];
    const float* bv = (const float*)d_in[8];
    const float* wo = (const float*)d_in[9];
    const float* bo = (const float*)d_in[10];
    float* out = (float*)d_out;

    char* ws = (char*)d_ws;
    __bf16* WT  = (__bf16*)(ws);                       // 8 MB
    __bf16* Qw  = (__bf16*)(ws + ((size_t)8  << 20));
    __bf16* Kw  = (__bf16*)(ws + ((size_t)16 << 20));
    __bf16* Vtw = (__bf16*)(ws + ((size_t)24 << 20));
    __bf16* Ow  = (__bf16*)(ws + ((size_t)32 << 20));  // 8 MB

    // bf16 activation scratch: Xq aliases Ow (dead until attn writes it);
    // Xk/Xv live in d_out (16.8 MB fp32; dead until out_proj writes it).
    __bf16* Xq = Ow;
    __bf16* Xk = (__bf16*)d_out;
    __bf16* Xv = (__bf16*)d_out + 4194304;

    prep_all<<<dim3(32, 32, 7), dim3(256), 0, stream>>>(
        wq, wk, wv, wo, query, key_, value, WT, Xq, Xk, Xv);
    proj_fast3<<<dim3(8, 32, 3), dim3(256), 0, stream>>>(
        Xq, Xk, Xv, WT, bq, bk, bv, Qw, Kw, Vtw);
    attn_kernel<<<dim3(16, 32), dim3(256), 0, stream>>>(Qw, Kw, Vtw, Ow);
    out_proj_fast64<<<dim3(16, 32), dim3(256), 0, stream>>>(
        Ow, WT + 3 * 1048576, bo, out);
}